// Round 1
// baseline (156.944 us; speedup 1.0000x reference)
//
#include <hip/hip_runtime.h>

#define SPB 16  // samples per block in the MLP kernel

__device__ __forceinline__ float shflx(float v, int m) {
    return __shfl_xor(v, m, 64);
}

// One wave = one sample. State: 256 complex amps, 4 per lane.
// idx = lane*4 + j. qubit q <-> idx bit (7-q). Lane bit (5-q) for q=0..5;
// qubit 6 = j bit1, qubit 7 = j bit0.
__global__ __launch_bounds__(256) void vqc_z_kernel(
    const float* __restrict__ x,      // (B,256)
    const float* __restrict__ theta,  // (3,8)
    const float* __restrict__ phi,    // (3,8)
    float* __restrict__ zout,         // (B,8)
    int B)
{
    const int lane = threadIdx.x & 63;
    const int s = (blockIdx.x << 2) + (threadIdx.x >> 6);
    if (s >= B) return;

    // ---- per-row min/max ----
    float4 xv = reinterpret_cast<const float4*>(x + (size_t)s * 256)[lane];
    float mn = fminf(fminf(xv.x, xv.y), fminf(xv.z, xv.w));
    float mx = fmaxf(fmaxf(xv.x, xv.y), fmaxf(xv.z, xv.w));
    #pragma unroll
    for (int m = 1; m < 64; m <<= 1) {
        mn = fminf(mn, shflx(mn, m));
        mx = fmaxf(mx, shflx(mx, m));
    }
    // half-angle scale: angle = (x-mn)/(mx-mn+1e-8)*(pi/2); we need angle/2
    const float scale = 0.78539816339744831f / (mx - mn + 1e-8f);

    // broadcast x[s,0..7]
    float xq[8];
    xq[0] = __shfl(xv.x, 0); xq[1] = __shfl(xv.y, 0);
    xq[2] = __shfl(xv.z, 0); xq[3] = __shfl(xv.w, 0);
    xq[4] = __shfl(xv.x, 1); xq[5] = __shfl(xv.y, 1);
    xq[6] = __shfl(xv.z, 1); xq[7] = __shfl(xv.w, 1);

    float cq[8], sq[8];
    #pragma unroll
    for (int q = 0; q < 8; ++q) {
        float a = (xq[q] - mn) * scale;
        cq[q] = __cosf(a);
        sq[q] = __sinf(a);
    }

    // ---- product-state init (encoding RY on |0>) ----
    float p05 = 1.f;
    #pragma unroll
    for (int q = 0; q < 6; ++q)
        p05 *= ((lane >> (5 - q)) & 1) ? sq[q] : cq[q];
    float re[4], im[4];
    re[0] = p05 * cq[6] * cq[7];
    re[1] = p05 * cq[6] * sq[7];
    re[2] = p05 * sq[6] * cq[7];
    re[3] = p05 * sq[6] * sq[7];
    im[0] = im[1] = im[2] = im[3] = 0.f;

    for (int l = 0; l < 3; ++l) {
        // ---- RY layer ----
        #pragma unroll
        for (int q = 0; q < 6; ++q) {
            float th = 0.5f * theta[l * 8 + q];
            float ct = __cosf(th), st = __sinf(th);
            float sg = ((lane >> (5 - q)) & 1) ? st : -st;  // bit0: c*own - s*oth; bit1: c*own + s*oth
            const int m = 1 << (5 - q);
            #pragma unroll
            for (int j = 0; j < 4; ++j) {
                float orr = shflx(re[j], m), oi = shflx(im[j], m);
                re[j] = fmaf(ct, re[j], sg * orr);
                im[j] = fmaf(ct, im[j], sg * oi);
            }
        }
        {   // q=6: pairs (0,2),(1,3)
            float th = 0.5f * theta[l * 8 + 6];
            float ct = __cosf(th), st = __sinf(th);
            #pragma unroll
            for (int j = 0; j < 2; ++j) {
                float r0 = re[j], i0 = im[j], r1 = re[j + 2], i1 = im[j + 2];
                re[j]     = fmaf(ct, r0, -st * r1);
                im[j]     = fmaf(ct, i0, -st * i1);
                re[j + 2] = fmaf(ct, r1,  st * r0);
                im[j + 2] = fmaf(ct, i1,  st * i0);
            }
        }
        {   // q=7: pairs (0,1),(2,3)
            float th = 0.5f * theta[l * 8 + 7];
            float ct = __cosf(th), st = __sinf(th);
            #pragma unroll
            for (int j = 0; j < 4; j += 2) {
                float r0 = re[j], i0 = im[j], r1 = re[j + 1], i1 = im[j + 1];
                re[j]     = fmaf(ct, r0, -st * r1);
                im[j]     = fmaf(ct, i0, -st * i1);
                re[j + 1] = fmaf(ct, r1,  st * r0);
                im[j + 1] = fmaf(ct, i1,  st * i0);
            }
        }
        // ---- CNOT ring, in order q=0..7 (order matters) ----
        #pragma unroll
        for (int q = 0; q < 5; ++q) {  // control lane bit 5-q, target lane bit 4-q
            const int tm = 1 << (4 - q);
            const bool cb = (lane >> (5 - q)) & 1;
            #pragma unroll
            for (int j = 0; j < 4; ++j) {
                float orr = shflx(re[j], tm), oi = shflx(im[j], tm);
                re[j] = cb ? orr : re[j];
                im[j] = cb ? oi  : im[j];
            }
        }
        {   // q=5: control lane bit0, target j-bit1: swap (0,2),(1,3) when control set
            const bool cb = lane & 1;
            float t;
            t = re[0]; re[0] = cb ? re[2] : re[0]; re[2] = cb ? t : re[2];
            t = im[0]; im[0] = cb ? im[2] : im[0]; im[2] = cb ? t : im[2];
            t = re[1]; re[1] = cb ? re[3] : re[1]; re[3] = cb ? t : re[3];
            t = im[1]; im[1] = cb ? im[3] : im[1]; im[3] = cb ? t : im[3];
        }
        {   // q=6: control j-bit1, target j-bit0: unconditional swap of amps 2,3
            float t;
            t = re[2]; re[2] = re[3]; re[3] = t;
            t = im[2]; im[2] = im[3]; im[3] = t;
        }
        {   // q=7: control j-bit0, target lane bit5: exchange odd-j amps with lane^32
            re[1] = shflx(re[1], 32); im[1] = shflx(im[1], 32);
            re[3] = shflx(re[3], 32); im[3] = shflx(im[3], 32);
        }
        // ---- RZ layer fused into one phase rotation per amplitude ----
        // bit=1 -> +phi/2, bit=0 -> -phi/2
        float al = 0.f;
        #pragma unroll
        for (int q = 0; q < 6; ++q) {
            float h = 0.5f * phi[l * 8 + q];
            al += ((lane >> (5 - q)) & 1) ? h : -h;
        }
        float h6 = 0.5f * phi[l * 8 + 6], h7 = 0.5f * phi[l * 8 + 7];
        float ajs[4] = { al - h6 - h7, al - h6 + h7, al + h6 - h7, al + h6 + h7 };
        #pragma unroll
        for (int j = 0; j < 4; ++j) {
            float c = __cosf(ajs[j]), sn = __sinf(ajs[j]);
            float r = re[j], i = im[j];
            re[j] = r * c - i * sn;
            im[j] = fmaf(r, sn, i * c);
        }
    }

    // ---- Z expectations ----
    float p[4];
    #pragma unroll
    for (int j = 0; j < 4; ++j) p[j] = re[j] * re[j] + im[j] * im[j];
    float w  = p[0] + p[1] + p[2] + p[3];        // WHT input -> z for qubits 0..5
    float s6 = (p[0] + p[1]) - (p[2] + p[3]);    // sign by j-bit1 (qubit 6)
    float s7 = (p[0] - p[1]) + (p[2] - p[3]);    // sign by j-bit0 (qubit 7)
    #pragma unroll
    for (int m = 1; m < 64; m <<= 1) {
        float t = shflx(w, m);
        w = (lane & m) ? (t - w) : (w + t);      // Walsh-Hadamard butterfly
        s6 += shflx(s6, m);
        s7 += shflx(s7, m);
    }
    // after WHT: lane (1<<k) holds sum_l (-1)^{lane bit k} = z for qubit 5-k
    const int lq = lane & 7;
    const int src = (lq < 6) ? (1 << (5 - lq)) : 0;
    float zw = __shfl(w, src);                   // all lanes active
    float zval = (lq == 6) ? s6 : (lq == 7) ? s7 : zw;
    if (lane < 8) zout[s * 8 + lane] = zval;
}

// out = x + relu(z@W1+b1)@W2 + b2 ; 16 samples per 256-thread block.
__global__ __launch_bounds__(256) void vqc_mlp_kernel(
    const float* __restrict__ x,
    const float* __restrict__ z,    // (B,8)
    const float* __restrict__ W1,   // (8,128)
    const float* __restrict__ b1,   // (128)
    const float* __restrict__ W2,   // (128,256)
    const float* __restrict__ b2,   // (256)
    float* __restrict__ out,
    int B)
{
    __shared__ float zs[8][SPB];
    __shared__ float hs[128][SPB];
    __shared__ float w1s[8 * 128];
    __shared__ float b1s[128];
    const int t = threadIdx.x;
    const int s0 = blockIdx.x * SPB;

    if (t < 8 * SPB) {
        int i = t >> 3, q = t & 7;
        int srow = s0 + i;
        zs[q][i] = (srow < B) ? z[(size_t)srow * 8 + q] : 0.f;
    }
    #pragma unroll
    for (int i = t; i < 1024; i += 256) w1s[i] = W1[i];
    if (t < 128) b1s[t] = b1[t];
    __syncthreads();

    // h[j][s] = relu(b1[j] + sum_q z[s][q] * W1[q][j])
    {
        const int ss = t & (SPB - 1);
        const int j0 = t >> 4;   // 16 j-groups
        #pragma unroll
        for (int i = 0; i < 8; ++i) {
            const int j = j0 + 16 * i;
            float acc = b1s[j];
            #pragma unroll
            for (int q = 0; q < 8; ++q)
                acc = fmaf(zs[q][ss], w1s[q * 128 + j], acc);
            hs[j][ss] = fmaxf(acc, 0.f);
        }
    }
    __syncthreads();

    // each thread owns output column d = t for all SPB samples
    float acc[SPB];
    #pragma unroll
    for (int i = 0; i < SPB; ++i) acc[i] = 0.f;
    #pragma unroll 4
    for (int k = 0; k < 128; ++k) {
        const float wv = W2[k * 256 + t];
        #pragma unroll
        for (int i = 0; i < SPB; ++i)
            acc[i] = fmaf(hs[k][i], wv, acc[i]);
    }
    const float bb = b2[t];
    #pragma unroll
    for (int i = 0; i < SPB; ++i) {
        const int srow = s0 + i;
        if (srow < B) {
            size_t o = (size_t)srow * 256 + t;
            out[o] = x[o] + bb + acc[i];
        }
    }
}

extern "C" void kernel_launch(void* const* d_in, const int* in_sizes, int n_in,
                              void* d_out, int out_size, void* d_ws, size_t ws_size,
                              hipStream_t stream) {
    const float* x     = (const float*)d_in[0];
    const float* theta = (const float*)d_in[1];
    const float* phi   = (const float*)d_in[2];
    const float* W1    = (const float*)d_in[3];
    const float* b1    = (const float*)d_in[4];
    const float* W2    = (const float*)d_in[5];
    const float* b2    = (const float*)d_in[6];
    float* out = (float*)d_out;
    const int B = in_sizes[0] / 256;
    float* zbuf = (float*)d_ws;  // B*8 floats = 512 KB scratch

    vqc_z_kernel<<<dim3((B + 3) / 4), dim3(256), 0, stream>>>(x, theta, phi, zbuf, B);
    vqc_mlp_kernel<<<dim3((B + SPB - 1) / SPB), dim3(256), 0, stream>>>(
        x, zbuf, W1, b1, W2, b2, out, B);
}

// Round 2
// 135.326 us; speedup vs baseline: 1.1597x; 1.1597x over previous
//
#include <hip/hip_runtime.h>
#include <hip/hip_bf16.h>

typedef __attribute__((ext_vector_type(8))) short short8;
typedef __attribute__((ext_vector_type(4))) float float4v;

__device__ __forceinline__ float shflx(float v, int m) {
    return __shfl_xor(v, m, 64);
}

__device__ __forceinline__ unsigned short f2bf(float f) {
    union { __hip_bfloat16 h; unsigned short u; } cv;
    cv.h = __float2bfloat16(f);
    return cv.u;
}

// ---------------------------------------------------------------------------
// K1: build the fixed circuit unitary U (256x256 complex) column by column.
// One wave simulates U e_j (basis-state init, verified round-1 circuit code).
// Stores Bmat (512,256) bf16 row-major: rows 0..255 = U_re[k'][j] with j the
// column, rows 256..511 = U_im.  Block 64 transposes W2 -> W2T (256,128) bf16.
// ---------------------------------------------------------------------------
__global__ __launch_bounds__(256) void vqc_build_u_kernel(
    const float* __restrict__ theta,  // (3,8)
    const float* __restrict__ phi,    // (3,8)
    const float* __restrict__ W2,     // (128,256)
    unsigned short* __restrict__ Bmat,  // (512,256) bf16
    unsigned short* __restrict__ W2T)   // (256,128) bf16
{
    if (blockIdx.x == 64) {
        for (int idx = threadIdx.x; idx < 128 * 256; idx += 256) {
            int k = idx >> 8, n = idx & 255;
            W2T[n * 128 + k] = f2bf(W2[idx]);
        }
        return;
    }
    const int lane = threadIdx.x & 63;
    const int j = (blockIdx.x << 2) + (threadIdx.x >> 6);  // column 0..255

    // init state = e_j ; amp index k' = lane*4 + jj
    float re[4], im[4];
    #pragma unroll
    for (int jj = 0; jj < 4; ++jj) {
        re[jj] = (lane * 4 + jj == j) ? 1.f : 0.f;
        im[jj] = 0.f;
    }

    for (int l = 0; l < 3; ++l) {
        // ---- RY layer ----
        #pragma unroll
        for (int q = 0; q < 6; ++q) {
            float th = 0.5f * theta[l * 8 + q];
            float ct = __cosf(th), st = __sinf(th);
            float sg = ((lane >> (5 - q)) & 1) ? st : -st;
            const int m = 1 << (5 - q);
            #pragma unroll
            for (int jj = 0; jj < 4; ++jj) {
                float orr = shflx(re[jj], m), oi = shflx(im[jj], m);
                re[jj] = fmaf(ct, re[jj], sg * orr);
                im[jj] = fmaf(ct, im[jj], sg * oi);
            }
        }
        {   // q=6
            float th = 0.5f * theta[l * 8 + 6];
            float ct = __cosf(th), st = __sinf(th);
            #pragma unroll
            for (int jj = 0; jj < 2; ++jj) {
                float r0 = re[jj], i0 = im[jj], r1 = re[jj + 2], i1 = im[jj + 2];
                re[jj]     = fmaf(ct, r0, -st * r1);
                im[jj]     = fmaf(ct, i0, -st * i1);
                re[jj + 2] = fmaf(ct, r1,  st * r0);
                im[jj + 2] = fmaf(ct, i1,  st * i0);
            }
        }
        {   // q=7
            float th = 0.5f * theta[l * 8 + 7];
            float ct = __cosf(th), st = __sinf(th);
            #pragma unroll
            for (int jj = 0; jj < 4; jj += 2) {
                float r0 = re[jj], i0 = im[jj], r1 = re[jj + 1], i1 = im[jj + 1];
                re[jj]     = fmaf(ct, r0, -st * r1);
                im[jj]     = fmaf(ct, i0, -st * i1);
                re[jj + 1] = fmaf(ct, r1,  st * r0);
                im[jj + 1] = fmaf(ct, i1,  st * i0);
            }
        }
        // ---- CNOT ring q=0..7 ----
        #pragma unroll
        for (int q = 0; q < 5; ++q) {
            const int tm = 1 << (4 - q);
            const bool cb = (lane >> (5 - q)) & 1;
            #pragma unroll
            for (int jj = 0; jj < 4; ++jj) {
                float orr = shflx(re[jj], tm), oi = shflx(im[jj], tm);
                re[jj] = cb ? orr : re[jj];
                im[jj] = cb ? oi  : im[jj];
            }
        }
        {   const bool cb = lane & 1;  // q=5
            float t;
            t = re[0]; re[0] = cb ? re[2] : re[0]; re[2] = cb ? t : re[2];
            t = im[0]; im[0] = cb ? im[2] : im[0]; im[2] = cb ? t : im[2];
            t = re[1]; re[1] = cb ? re[3] : re[1]; re[3] = cb ? t : re[3];
            t = im[1]; im[1] = cb ? im[3] : im[1]; im[3] = cb ? t : im[3];
        }
        {   float t;                    // q=6
            t = re[2]; re[2] = re[3]; re[3] = t;
            t = im[2]; im[2] = im[3]; im[3] = t;
        }
        {   // q=7
            re[1] = shflx(re[1], 32); im[1] = shflx(im[1], 32);
            re[3] = shflx(re[3], 32); im[3] = shflx(im[3], 32);
        }
        // ---- fused RZ phase ----
        float al = 0.f;
        #pragma unroll
        for (int q = 0; q < 6; ++q) {
            float h = 0.5f * phi[l * 8 + q];
            al += ((lane >> (5 - q)) & 1) ? h : -h;
        }
        float h6 = 0.5f * phi[l * 8 + 6], h7 = 0.5f * phi[l * 8 + 7];
        float ajs[4] = { al - h6 - h7, al - h6 + h7, al + h6 - h7, al + h6 + h7 };
        #pragma unroll
        for (int jj = 0; jj < 4; ++jj) {
            float cc = __cosf(ajs[jj]), sn = __sinf(ajs[jj]);
            float r = re[jj], i = im[jj];
            re[jj] = r * cc - i * sn;
            im[jj] = fmaf(r, sn, i * cc);
        }
    }

    // write column j of U_re / U_im (bf16), row index k' = lane*4+jj
    #pragma unroll
    for (int jj = 0; jj < 4; ++jj) {
        int kp = lane * 4 + jj;
        Bmat[(size_t)kp * 256 + j]         = f2bf(re[jj]);
        Bmat[(size_t)(kp + 256) * 256 + j] = f2bf(im[jj]);
    }
}

// ---------------------------------------------------------------------------
// K2: encode. Per-sample min/max normalize, 8 RY half-angles, product state
// -> Psi (B,256) bf16 row-major. One wave per sample.
// ---------------------------------------------------------------------------
__global__ __launch_bounds__(256) void vqc_encode_kernel(
    const float* __restrict__ x,       // (B,256)
    unsigned short* __restrict__ Psi,  // (B,256) bf16
    int B)
{
    const int lane = threadIdx.x & 63;
    const int s = (blockIdx.x << 2) + (threadIdx.x >> 6);
    if (s >= B) return;

    float4 xv = reinterpret_cast<const float4*>(x + (size_t)s * 256)[lane];
    float mn = fminf(fminf(xv.x, xv.y), fminf(xv.z, xv.w));
    float mx = fmaxf(fmaxf(xv.x, xv.y), fmaxf(xv.z, xv.w));
    #pragma unroll
    for (int m = 1; m < 64; m <<= 1) {
        mn = fminf(mn, shflx(mn, m));
        mx = fmaxf(mx, shflx(mx, m));
    }
    const float scale = 0.78539816339744831f / (mx - mn + 1e-8f);  // (pi/2)/2 / range

    float xq[8];
    xq[0] = __shfl(xv.x, 0); xq[1] = __shfl(xv.y, 0);
    xq[2] = __shfl(xv.z, 0); xq[3] = __shfl(xv.w, 0);
    xq[4] = __shfl(xv.x, 1); xq[5] = __shfl(xv.y, 1);
    xq[6] = __shfl(xv.z, 1); xq[7] = __shfl(xv.w, 1);

    float cq[8], sq[8];
    #pragma unroll
    for (int q = 0; q < 8; ++q) {
        float a = (xq[q] - mn) * scale;
        cq[q] = __cosf(a);
        sq[q] = __sinf(a);
    }

    float p05 = 1.f;
    #pragma unroll
    for (int q = 0; q < 6; ++q)
        p05 *= ((lane >> (5 - q)) & 1) ? sq[q] : cq[q];

    ushort4 pk;
    pk.x = f2bf(p05 * cq[6] * cq[7]);
    pk.y = f2bf(p05 * cq[6] * sq[7]);
    pk.z = f2bf(p05 * sq[6] * cq[7]);
    pk.w = f2bf(p05 * sq[6] * sq[7]);
    *reinterpret_cast<ushort4*>(Psi + (size_t)s * 256 + lane * 4) = pk;
}

// ---------------------------------------------------------------------------
// K3: fused  Phi = Psi @ [U_re;U_im]^T  (bf16 MFMA)  ->  probs -> z -> MLP
//            out = x + relu(z@W1+b1)@W2 + b2
// Block: 256 threads (4 waves), 32 samples. Wave w owns output cols
// [w*64, w*64+64) in both GEMMs. MFMA frag maps (HW-verified):
//   A/B: row = lane&15, k = (lane>>4)*8 + j ; C/D: col = lane&15,
//   row = (lane>>4)*4 + reg.
// ---------------------------------------------------------------------------
__global__ __launch_bounds__(256) void vqc_fused_kernel(
    const float* __restrict__ x,
    const unsigned short* __restrict__ Psi,   // (B,256) bf16
    const unsigned short* __restrict__ Bmat,  // (512,256) bf16
    const unsigned short* __restrict__ W2T,   // (256,128) bf16
    const float* __restrict__ W1,             // (8,128)
    const float* __restrict__ b1,             // (128)
    const float* __restrict__ b2,             // (256)
    float* __restrict__ out,
    int B)
{
    __shared__ float p_lds[32][260];          // probs, padded stride
    __shared__ float z_lds[32][8];
    __shared__ unsigned short h_lds[32][136]; // h bf16, stride 136 (272B, 16B-mult)

    const int t = threadIdx.x;
    const int lane = t & 63;
    const int w = t >> 6;
    const int c = lane & 15;
    const int quad = lane >> 4;
    const int s0 = blockIdx.x * 32;

    // ---- GEMM1: Phi_{re,im}[s][n] = sum_i Psi[s][i] * U_{re,im}[n][i] ----
    float4v acc[2][8];
    #pragma unroll
    for (int h = 0; h < 2; ++h)
        #pragma unroll
        for (int tt = 0; tt < 8; ++tt)
            acc[h][tt] = (float4v){0.f, 0.f, 0.f, 0.f};

    for (int kk = 0; kk < 8; ++kk) {
        const int ko = kk * 32 + quad * 8;
        short8 a0 = *(const short8*)(Psi + (size_t)(s0 + c) * 256 + ko);
        short8 a1 = *(const short8*)(Psi + (size_t)(s0 + 16 + c) * 256 + ko);
        #pragma unroll
        for (int tt = 0; tt < 4; ++tt) {
            const int nr = (w * 4 + tt) * 16 + c;
            short8 bre = *(const short8*)(Bmat + (size_t)nr * 256 + ko);
            short8 bim = *(const short8*)(Bmat + (size_t)(nr + 256) * 256 + ko);
            acc[0][tt]     = __builtin_amdgcn_mfma_f32_16x16x32_bf16(a0, bre, acc[0][tt], 0, 0, 0);
            acc[1][tt]     = __builtin_amdgcn_mfma_f32_16x16x32_bf16(a1, bre, acc[1][tt], 0, 0, 0);
            acc[0][tt + 4] = __builtin_amdgcn_mfma_f32_16x16x32_bf16(a0, bim, acc[0][tt + 4], 0, 0, 0);
            acc[1][tt + 4] = __builtin_amdgcn_mfma_f32_16x16x32_bf16(a1, bim, acc[1][tt + 4], 0, 0, 0);
        }
    }

    // ---- probabilities into LDS ----
    #pragma unroll
    for (int h = 0; h < 2; ++h)
        #pragma unroll
        for (int tt = 0; tt < 4; ++tt) {
            const int n = (w * 4 + tt) * 16 + c;
            #pragma unroll
            for (int r = 0; r < 4; ++r) {
                const int m = h * 16 + quad * 4 + r;
                const float pr = acc[h][tt][r], pi = acc[h][tt + 4][r];
                p_lds[m][n] = pr * pr + pi * pi;
            }
        }
    __syncthreads();

    // ---- z_q[m] = sum_n (-1)^{bit(7-q) of n} p[m][n] ----
    {
        const int m = t >> 3, q = t & 7, sh = 7 - q;
        const float4* prow = (const float4*)&p_lds[m][0];
        float zv = 0.f;
        #pragma unroll 8
        for (int n4 = 0; n4 < 64; ++n4) {
            float4 pv = prow[n4];
            const int n = n4 * 4;
            zv += (((n + 0) >> sh) & 1) ? -pv.x : pv.x;
            zv += (((n + 1) >> sh) & 1) ? -pv.y : pv.y;
            zv += (((n + 2) >> sh) & 1) ? -pv.z : pv.z;
            zv += (((n + 3) >> sh) & 1) ? -pv.w : pv.w;
        }
        z_lds[m][q] = zv;
    }
    __syncthreads();

    // ---- MLP layer 1: h = relu(z @ W1 + b1), bf16 into h_lds ----
    {
        const int j = t & 127, ig = t >> 7;
        float w1v[8];
        #pragma unroll
        for (int q = 0; q < 8; ++q) w1v[q] = W1[q * 128 + j];
        const float b1v = b1[j];
        #pragma unroll
        for (int ii = 0; ii < 16; ++ii) {
            const int i = ig * 16 + ii;
            float a = b1v;
            #pragma unroll
            for (int q = 0; q < 8; ++q) a = fmaf(z_lds[i][q], w1v[q], a);
            h_lds[i][j] = f2bf(fmaxf(a, 0.f));
        }
    }
    __syncthreads();

    // ---- MLP layer 2 via MFMA: D = h @ W2 (W2T is (n,k) row-major) ----
    float4v acc2[2][4];
    #pragma unroll
    for (int h = 0; h < 2; ++h)
        #pragma unroll
        for (int tt = 0; tt < 4; ++tt)
            acc2[h][tt] = (float4v){0.f, 0.f, 0.f, 0.f};

    for (int kk = 0; kk < 4; ++kk) {
        const int ko = kk * 32 + quad * 8;
        short8 a0 = *(const short8*)(&h_lds[c][ko]);
        short8 a1 = *(const short8*)(&h_lds[16 + c][ko]);
        #pragma unroll
        for (int tt = 0; tt < 4; ++tt) {
            const int nr = (w * 4 + tt) * 16 + c;
            short8 bw = *(const short8*)(W2T + (size_t)nr * 128 + ko);
            acc2[0][tt] = __builtin_amdgcn_mfma_f32_16x16x32_bf16(a0, bw, acc2[0][tt], 0, 0, 0);
            acc2[1][tt] = __builtin_amdgcn_mfma_f32_16x16x32_bf16(a1, bw, acc2[1][tt], 0, 0, 0);
        }
    }

    // ---- epilogue: out = x + b2 + D ----
    #pragma unroll
    for (int h = 0; h < 2; ++h)
        #pragma unroll
        for (int tt = 0; tt < 4; ++tt) {
            const int n = (w * 4 + tt) * 16 + c;
            const float b2v = b2[n];
            #pragma unroll
            for (int r = 0; r < 4; ++r) {
                const int m = h * 16 + quad * 4 + r;
                const size_t idx = (size_t)(s0 + m) * 256 + n;
                out[idx] = x[idx] + b2v + acc2[h][tt][r];
            }
        }
}

extern "C" void kernel_launch(void* const* d_in, const int* in_sizes, int n_in,
                              void* d_out, int out_size, void* d_ws, size_t ws_size,
                              hipStream_t stream) {
    const float* x     = (const float*)d_in[0];
    const float* theta = (const float*)d_in[1];
    const float* phi   = (const float*)d_in[2];
    const float* W1    = (const float*)d_in[3];
    const float* b1    = (const float*)d_in[4];
    const float* W2    = (const float*)d_in[5];
    const float* b2    = (const float*)d_in[6];
    float* out = (float*)d_out;
    const int B = in_sizes[0] / 256;

    // workspace layout (bf16 shorts): Bmat (512,256) | W2T (256,128) | Psi (B,256)
    unsigned short* Bmat = (unsigned short*)d_ws;
    unsigned short* W2T  = Bmat + 512 * 256;
    unsigned short* Psi  = W2T + 256 * 128;

    vqc_build_u_kernel<<<dim3(65), dim3(256), 0, stream>>>(theta, phi, W2, Bmat, W2T);
    vqc_encode_kernel<<<dim3((B + 3) / 4), dim3(256), 0, stream>>>(x, Psi, B);
    vqc_fused_kernel<<<dim3(B / 32), dim3(256), 0, stream>>>(
        x, Psi, Bmat, W2T, W1, b1, b2, out, B);
}

// Round 3
// 108.243 us; speedup vs baseline: 1.4499x; 1.2502x over previous
//
#include <hip/hip_runtime.h>
#include <hip/hip_bf16.h>

typedef __attribute__((ext_vector_type(8))) short short8;
typedef __attribute__((ext_vector_type(4))) float float4v;

#define PSTRIDE   260  // floats  (p_lds row stride)
#define PSISTRIDE 264  // shorts  (psi_lds row stride; 132 dwords -> <=2-way banks)
#define HSTRIDE   136  // shorts  (h_lds row stride)

__device__ __forceinline__ float shflx(float v, int m) {
    return __shfl_xor(v, m, 64);
}

__device__ __forceinline__ unsigned short f2bf(float f) {
    union { __hip_bfloat16 h; unsigned short u; } cv;
    cv.h = __float2bfloat16(f);
    return cv.u;
}

// ---------------------------------------------------------------------------
// K1: blocks 0..63 build the circuit unitary U (256x256 complex), one wave
// per column (verified round-1/2 circuit code). Bmat (512,256) bf16:
// rows 0..255 = U_re[n][i], rows 256..511 = U_im[n][i].
// Blocks 64..95: vectorized W2 -> W2T (256,128) bf16 transpose.
// ---------------------------------------------------------------------------
__global__ __launch_bounds__(256) void vqc_build_u_kernel(
    const float* __restrict__ theta,  // (3,8)
    const float* __restrict__ phi,    // (3,8)
    const float* __restrict__ W2,     // (128,256)
    unsigned short* __restrict__ Bmat,
    unsigned short* __restrict__ W2T)
{
    const int b = blockIdx.x;
    if (b >= 64) {
        const int k0 = (b - 64) * 4;     // 32 blocks cover k=0..127
        const int n = threadIdx.x;       // coalesced across n
        ushort4 pk;
        pk.x = f2bf(W2[(k0 + 0) * 256 + n]);
        pk.y = f2bf(W2[(k0 + 1) * 256 + n]);
        pk.z = f2bf(W2[(k0 + 2) * 256 + n]);
        pk.w = f2bf(W2[(k0 + 3) * 256 + n]);
        *reinterpret_cast<ushort4*>(W2T + n * 128 + k0) = pk;
        return;
    }
    const int lane = threadIdx.x & 63;
    const int j = (b << 2) + (threadIdx.x >> 6);  // column 0..255

    float re[4], im[4];
    #pragma unroll
    for (int jj = 0; jj < 4; ++jj) {
        re[jj] = (lane * 4 + jj == j) ? 1.f : 0.f;
        im[jj] = 0.f;
    }

    for (int l = 0; l < 3; ++l) {
        // ---- RY layer ----
        #pragma unroll
        for (int q = 0; q < 6; ++q) {
            float th = 0.5f * theta[l * 8 + q];
            float ct = __cosf(th), st = __sinf(th);
            float sg = ((lane >> (5 - q)) & 1) ? st : -st;
            const int m = 1 << (5 - q);
            #pragma unroll
            for (int jj = 0; jj < 4; ++jj) {
                float orr = shflx(re[jj], m), oi = shflx(im[jj], m);
                re[jj] = fmaf(ct, re[jj], sg * orr);
                im[jj] = fmaf(ct, im[jj], sg * oi);
            }
        }
        {   // q=6
            float th = 0.5f * theta[l * 8 + 6];
            float ct = __cosf(th), st = __sinf(th);
            #pragma unroll
            for (int jj = 0; jj < 2; ++jj) {
                float r0 = re[jj], i0 = im[jj], r1 = re[jj + 2], i1 = im[jj + 2];
                re[jj]     = fmaf(ct, r0, -st * r1);
                im[jj]     = fmaf(ct, i0, -st * i1);
                re[jj + 2] = fmaf(ct, r1,  st * r0);
                im[jj + 2] = fmaf(ct, i1,  st * i0);
            }
        }
        {   // q=7
            float th = 0.5f * theta[l * 8 + 7];
            float ct = __cosf(th), st = __sinf(th);
            #pragma unroll
            for (int jj = 0; jj < 4; jj += 2) {
                float r0 = re[jj], i0 = im[jj], r1 = re[jj + 1], i1 = im[jj + 1];
                re[jj]     = fmaf(ct, r0, -st * r1);
                im[jj]     = fmaf(ct, i0, -st * i1);
                re[jj + 1] = fmaf(ct, r1,  st * r0);
                im[jj + 1] = fmaf(ct, i1,  st * i0);
            }
        }
        // ---- CNOT ring q=0..7 ----
        #pragma unroll
        for (int q = 0; q < 5; ++q) {
            const int tm = 1 << (4 - q);
            const bool cb = (lane >> (5 - q)) & 1;
            #pragma unroll
            for (int jj = 0; jj < 4; ++jj) {
                float orr = shflx(re[jj], tm), oi = shflx(im[jj], tm);
                re[jj] = cb ? orr : re[jj];
                im[jj] = cb ? oi  : im[jj];
            }
        }
        {   const bool cb = lane & 1;  // q=5
            float t;
            t = re[0]; re[0] = cb ? re[2] : re[0]; re[2] = cb ? t : re[2];
            t = im[0]; im[0] = cb ? im[2] : im[0]; im[2] = cb ? t : im[2];
            t = re[1]; re[1] = cb ? re[3] : re[1]; re[3] = cb ? t : re[3];
            t = im[1]; im[1] = cb ? im[3] : im[1]; im[3] = cb ? t : im[3];
        }
        {   float t;                   // q=6
            t = re[2]; re[2] = re[3]; re[3] = t;
            t = im[2]; im[2] = im[3]; im[3] = t;
        }
        {   // q=7
            re[1] = shflx(re[1], 32); im[1] = shflx(im[1], 32);
            re[3] = shflx(re[3], 32); im[3] = shflx(im[3], 32);
        }
        // ---- fused RZ phase ----
        float al = 0.f;
        #pragma unroll
        for (int q = 0; q < 6; ++q) {
            float h = 0.5f * phi[l * 8 + q];
            al += ((lane >> (5 - q)) & 1) ? h : -h;
        }
        float h6 = 0.5f * phi[l * 8 + 6], h7 = 0.5f * phi[l * 8 + 7];
        float ajs[4] = { al - h6 - h7, al - h6 + h7, al + h6 - h7, al + h6 + h7 };
        #pragma unroll
        for (int jj = 0; jj < 4; ++jj) {
            float cc = __cosf(ajs[jj]), sn = __sinf(ajs[jj]);
            float r = re[jj], i = im[jj];
            re[jj] = r * cc - i * sn;
            im[jj] = fmaf(r, sn, i * cc);
        }
    }

    #pragma unroll
    for (int jj = 0; jj < 4; ++jj) {
        int kp = lane * 4 + jj;
        Bmat[(size_t)kp * 256 + j]         = f2bf(re[jj]);
        Bmat[(size_t)(kp + 256) * 256 + j] = f2bf(im[jj]);
    }
}

// ---------------------------------------------------------------------------
// K2: mega-fused. 32 samples / 256-thread block.
//   encode -> psi_lds (bf16) -> GEMM1 (MFMA, B from L2) -> probs -> z ->
//   MLP1 -> GEMM2 (MFMA) -> out = x + b2 + D
// LDS: psi / p / h alias one 33280 B region (sequential phases, synced).
// MFMA frag maps (HW-verified): A/B row=lane&15, k=(lane>>4)*8+j;
//                               C/D col=lane&15, row=(lane>>4)*4+reg.
// ---------------------------------------------------------------------------
__global__ __launch_bounds__(256) void vqc_mega_kernel(
    const float* __restrict__ x,
    const unsigned short* __restrict__ Bmat,  // (512,256) bf16
    const unsigned short* __restrict__ W2T,   // (256,128) bf16
    const float* __restrict__ W1,             // (8,128)
    const float* __restrict__ b1,             // (128)
    const float* __restrict__ b2,             // (256)
    float* __restrict__ out,
    int B)
{
    __shared__ __align__(16) char smem[32 * PSTRIDE * 4];  // 33280 B
    __shared__ float z_lds[32][8];
    float (*p_lds)[PSTRIDE] = (float(*)[PSTRIDE])smem;
    unsigned short (*psi_lds)[PSISTRIDE] = (unsigned short(*)[PSISTRIDE])smem;
    unsigned short (*h_lds)[HSTRIDE] = (unsigned short(*)[HSTRIDE])smem;

    const int t = threadIdx.x;
    const int lane = t & 63;
    const int w = t >> 6;
    const int c = lane & 15;
    const int quad = lane >> 4;
    const int s0 = blockIdx.x * 32;

    // ---- encode: 8 threads per sample ----
    {
        const int g = t >> 3;        // local sample 0..31
        const int sub = t & 7;       // column chunk sub*32..sub*32+31
        const float4* xr = reinterpret_cast<const float4*>(x + (size_t)(s0 + g) * 256) + sub * 8;
        float4 v0 = xr[0], v1 = xr[1], v2 = xr[2], v3 = xr[3];
        float4 v4 = xr[4], v5 = xr[5], v6 = xr[6], v7 = xr[7];
        float mn = fminf(fminf(fminf(v0.x, v0.y), fminf(v0.z, v0.w)),
                         fminf(fminf(v1.x, v1.y), fminf(v1.z, v1.w)));
        mn = fminf(mn, fminf(fminf(fminf(v2.x, v2.y), fminf(v2.z, v2.w)),
                             fminf(fminf(v3.x, v3.y), fminf(v3.z, v3.w))));
        mn = fminf(mn, fminf(fminf(fminf(v4.x, v4.y), fminf(v4.z, v4.w)),
                             fminf(fminf(v5.x, v5.y), fminf(v5.z, v5.w))));
        mn = fminf(mn, fminf(fminf(fminf(v6.x, v6.y), fminf(v6.z, v6.w)),
                             fminf(fminf(v7.x, v7.y), fminf(v7.z, v7.w))));
        float mx = fmaxf(fmaxf(fmaxf(v0.x, v0.y), fmaxf(v0.z, v0.w)),
                         fmaxf(fmaxf(v1.x, v1.y), fmaxf(v1.z, v1.w)));
        mx = fmaxf(mx, fmaxf(fmaxf(fmaxf(v2.x, v2.y), fmaxf(v2.z, v2.w)),
                             fmaxf(fmaxf(v3.x, v3.y), fmaxf(v3.z, v3.w))));
        mx = fmaxf(mx, fmaxf(fmaxf(fmaxf(v4.x, v4.y), fmaxf(v4.z, v4.w)),
                             fmaxf(fmaxf(v5.x, v5.y), fmaxf(v5.z, v5.w))));
        mx = fmaxf(mx, fmaxf(fmaxf(fmaxf(v6.x, v6.y), fmaxf(v6.z, v6.w)),
                             fmaxf(fmaxf(v7.x, v7.y), fmaxf(v7.z, v7.w))));
        #pragma unroll
        for (int m = 1; m < 8; m <<= 1) {
            mn = fminf(mn, shflx(mn, m));
            mx = fmaxf(mx, shflx(mx, m));
        }
        const float scale = 0.78539816339744831f / (mx - mn + 1e-8f);  // half-angle

        const int base = lane & 56;  // sub==0 lane of this sample group
        float xq[8];
        xq[0] = __shfl(v0.x, base); xq[1] = __shfl(v0.y, base);
        xq[2] = __shfl(v0.z, base); xq[3] = __shfl(v0.w, base);
        xq[4] = __shfl(v1.x, base); xq[5] = __shfl(v1.y, base);
        xq[6] = __shfl(v1.z, base); xq[7] = __shfl(v1.w, base);

        float cq[8], sq[8];
        #pragma unroll
        for (int q = 0; q < 8; ++q) {
            float a = (xq[q] - mn) * scale;
            cq[q] = __cosf(a);
            sq[q] = __sinf(a);
        }
        // amp idx = sub*32 + n ; qubit q <-> idx bit (7-q)
        float pref = ((sub >> 2) & 1 ? sq[0] : cq[0]) *
                     ((sub >> 1) & 1 ? sq[1] : cq[1]) *
                     ((sub >> 0) & 1 ? sq[2] : cq[2]);
        float p1[2], p2[4], p3[8], p4[16];
        p1[0] = pref * cq[3]; p1[1] = pref * sq[3];
        #pragma unroll
        for (int i = 0; i < 2; ++i) { p2[2*i] = p1[i] * cq[4]; p2[2*i+1] = p1[i] * sq[4]; }
        #pragma unroll
        for (int i = 0; i < 4; ++i) { p3[2*i] = p2[i] * cq[5]; p3[2*i+1] = p2[i] * sq[5]; }
        #pragma unroll
        for (int i = 0; i < 8; ++i) { p4[2*i] = p3[i] * cq[6]; p4[2*i+1] = p3[i] * sq[6]; }
        ushort2* dst = reinterpret_cast<ushort2*>(&psi_lds[g][sub * 32]);
        #pragma unroll
        for (int i = 0; i < 16; ++i) {
            ushort2 pk;
            pk.x = f2bf(p4[i] * cq[7]);
            pk.y = f2bf(p4[i] * sq[7]);
            dst[i] = pk;
        }
    }
    __syncthreads();

    // ---- GEMM1: Phi_{re,im}[s][n] = sum_i Psi[s][i] * U_{re,im}[n][i] ----
    float4v acc[2][8];
    #pragma unroll
    for (int h = 0; h < 2; ++h)
        #pragma unroll
        for (int tt = 0; tt < 8; ++tt)
            acc[h][tt] = (float4v){0.f, 0.f, 0.f, 0.f};

    #pragma unroll
    for (int kk = 0; kk < 8; ++kk) {
        const int ko = kk * 32 + quad * 8;
        short8 a0 = *(const short8*)(&psi_lds[c][ko]);
        short8 a1 = *(const short8*)(&psi_lds[16 + c][ko]);
        #pragma unroll
        for (int tt = 0; tt < 4; ++tt) {
            const int nr = (w * 4 + tt) * 16 + c;
            short8 bre = *(const short8*)(Bmat + (size_t)nr * 256 + ko);
            short8 bim = *(const short8*)(Bmat + (size_t)(nr + 256) * 256 + ko);
            acc[0][tt]     = __builtin_amdgcn_mfma_f32_16x16x32_bf16(a0, bre, acc[0][tt], 0, 0, 0);
            acc[1][tt]     = __builtin_amdgcn_mfma_f32_16x16x32_bf16(a1, bre, acc[1][tt], 0, 0, 0);
            acc[0][tt + 4] = __builtin_amdgcn_mfma_f32_16x16x32_bf16(a0, bim, acc[0][tt + 4], 0, 0, 0);
            acc[1][tt + 4] = __builtin_amdgcn_mfma_f32_16x16x32_bf16(a1, bim, acc[1][tt + 4], 0, 0, 0);
        }
    }
    __syncthreads();  // all psi reads done before p overwrites the region

    // ---- probabilities into LDS ----
    #pragma unroll
    for (int h = 0; h < 2; ++h)
        #pragma unroll
        for (int tt = 0; tt < 4; ++tt) {
            const int n = (w * 4 + tt) * 16 + c;
            #pragma unroll
            for (int r = 0; r < 4; ++r) {
                const int m = h * 16 + quad * 4 + r;
                const float pr = acc[h][tt][r], pi = acc[h][tt + 4][r];
                p_lds[m][n] = pr * pr + pi * pi;
            }
        }
    __syncthreads();

    // ---- z_q[m] = sum_n (-1)^{bit(7-q) of n} p[m][n] ----
    {
        const int m = t >> 3, q = t & 7, sh = 7 - q;
        const float4* prow = (const float4*)&p_lds[m][0];
        float zv = 0.f;
        #pragma unroll 8
        for (int n4 = 0; n4 < 64; ++n4) {
            float4 pv = prow[n4];
            const int n = n4 * 4;
            zv += (((n + 0) >> sh) & 1) ? -pv.x : pv.x;
            zv += (((n + 1) >> sh) & 1) ? -pv.y : pv.y;
            zv += (((n + 2) >> sh) & 1) ? -pv.z : pv.z;
            zv += (((n + 3) >> sh) & 1) ? -pv.w : pv.w;
        }
        z_lds[m][q] = zv;
    }
    __syncthreads();  // p reads done before h overwrites the region

    // ---- MLP layer 1: h = relu(z @ W1 + b1) -> bf16 h_lds ----
    {
        const int j = t & 127, ig = t >> 7;
        float w1v[8];
        #pragma unroll
        for (int q = 0; q < 8; ++q) w1v[q] = W1[q * 128 + j];
        const float b1v = b1[j];
        #pragma unroll
        for (int ii = 0; ii < 16; ++ii) {
            const int i = ig * 16 + ii;
            float a = b1v;
            #pragma unroll
            for (int q = 0; q < 8; ++q) a = fmaf(z_lds[i][q], w1v[q], a);
            h_lds[i][j] = f2bf(fmaxf(a, 0.f));
        }
    }
    __syncthreads();

    // ---- MLP layer 2 via MFMA ----
    float4v acc2[2][4];
    #pragma unroll
    for (int h = 0; h < 2; ++h)
        #pragma unroll
        for (int tt = 0; tt < 4; ++tt)
            acc2[h][tt] = (float4v){0.f, 0.f, 0.f, 0.f};

    #pragma unroll
    for (int kk = 0; kk < 4; ++kk) {
        const int ko = kk * 32 + quad * 8;
        short8 a0 = *(const short8*)(&h_lds[c][ko]);
        short8 a1 = *(const short8*)(&h_lds[16 + c][ko]);
        #pragma unroll
        for (int tt = 0; tt < 4; ++tt) {
            const int nr = (w * 4 + tt) * 16 + c;
            short8 bw = *(const short8*)(W2T + (size_t)nr * 128 + ko);
            acc2[0][tt] = __builtin_amdgcn_mfma_f32_16x16x32_bf16(a0, bw, acc2[0][tt], 0, 0, 0);
            acc2[1][tt] = __builtin_amdgcn_mfma_f32_16x16x32_bf16(a1, bw, acc2[1][tt], 0, 0, 0);
        }
    }

    // ---- epilogue: out = x + b2 + D (x rows L2-hot from encode) ----
    #pragma unroll
    for (int h = 0; h < 2; ++h)
        #pragma unroll
        for (int tt = 0; tt < 4; ++tt) {
            const int n = (w * 4 + tt) * 16 + c;
            const float b2v = b2[n];
            #pragma unroll
            for (int r = 0; r < 4; ++r) {
                const int m = h * 16 + quad * 4 + r;
                const size_t idx = (size_t)(s0 + m) * 256 + n;
                out[idx] = x[idx] + b2v + acc2[h][tt][r];
            }
        }
}

extern "C" void kernel_launch(void* const* d_in, const int* in_sizes, int n_in,
                              void* d_out, int out_size, void* d_ws, size_t ws_size,
                              hipStream_t stream) {
    const float* x     = (const float*)d_in[0];
    const float* theta = (const float*)d_in[1];
    const float* phi   = (const float*)d_in[2];
    const float* W1    = (const float*)d_in[3];
    const float* b1    = (const float*)d_in[4];
    const float* W2    = (const float*)d_in[5];
    const float* b2    = (const float*)d_in[6];
    float* out = (float*)d_out;
    const int B = in_sizes[0] / 256;

    unsigned short* Bmat = (unsigned short*)d_ws;   // (512,256) bf16
    unsigned short* W2T  = Bmat + 512 * 256;        // (256,128) bf16

    vqc_build_u_kernel<<<dim3(96), dim3(256), 0, stream>>>(theta, phi, W2, Bmat, W2T);
    vqc_mega_kernel<<<dim3(B / 32), dim3(256), 0, stream>>>(
        x, Bmat, W2T, W1, b1, b2, out, B);
}

// Round 4
// 98.696 us; speedup vs baseline: 1.5902x; 1.0967x over previous
//
#include <hip/hip_runtime.h>
#include <hip/hip_bf16.h>

typedef __attribute__((ext_vector_type(8))) short short8;
typedef __attribute__((ext_vector_type(4))) float float4v;

#define NS    64   // samples per mega block
#define PSTR  264  // psi/p row stride in shorts (132 dwords = +4 banks/row)
#define HSTR  136  // h row stride in shorts
#define ZPSTR 68   // zp row stride in floats

__device__ __forceinline__ float shflx(float v, int m) {
    return __shfl_xor(v, m, 64);
}

__device__ __forceinline__ unsigned short f2bf(float f) {
    union { __hip_bfloat16 h; unsigned short u; } cv;
    cv.h = __float2bfloat16(f);
    return cv.u;
}

__device__ __forceinline__ float bfbits(unsigned int u) {  // u has bf16 in high 16
    union { unsigned int u; float f; } cv;
    cv.u = u;
    return cv.f;
}

// ---------------------------------------------------------------------------
// K1: blocks 0..63 build circuit unitary U (256x256 complex), one wave/column
// (verified rounds 1-3). Bmat (512,256) bf16: rows 0..255 = U_re[n][k],
// rows 256..511 = U_im[n][k]. Blocks 64..95: W2 -> W2T (256,128) bf16.
// ---------------------------------------------------------------------------
__global__ __launch_bounds__(256) void vqc_build_u_kernel(
    const float* __restrict__ theta,
    const float* __restrict__ phi,
    const float* __restrict__ W2,
    unsigned short* __restrict__ Bmat,
    unsigned short* __restrict__ W2T)
{
    const int b = blockIdx.x;
    if (b >= 64) {
        const int k0 = (b - 64) * 4;
        const int n = threadIdx.x;
        ushort4 pk;
        pk.x = f2bf(W2[(k0 + 0) * 256 + n]);
        pk.y = f2bf(W2[(k0 + 1) * 256 + n]);
        pk.z = f2bf(W2[(k0 + 2) * 256 + n]);
        pk.w = f2bf(W2[(k0 + 3) * 256 + n]);
        *reinterpret_cast<ushort4*>(W2T + n * 128 + k0) = pk;
        return;
    }
    const int lane = threadIdx.x & 63;
    const int j = (b << 2) + (threadIdx.x >> 6);

    float re[4], im[4];
    #pragma unroll
    for (int jj = 0; jj < 4; ++jj) {
        re[jj] = (lane * 4 + jj == j) ? 1.f : 0.f;
        im[jj] = 0.f;
    }

    for (int l = 0; l < 3; ++l) {
        #pragma unroll
        for (int q = 0; q < 6; ++q) {
            float th = 0.5f * theta[l * 8 + q];
            float ct = __cosf(th), st = __sinf(th);
            float sg = ((lane >> (5 - q)) & 1) ? st : -st;
            const int m = 1 << (5 - q);
            #pragma unroll
            for (int jj = 0; jj < 4; ++jj) {
                float orr = shflx(re[jj], m), oi = shflx(im[jj], m);
                re[jj] = fmaf(ct, re[jj], sg * orr);
                im[jj] = fmaf(ct, im[jj], sg * oi);
            }
        }
        {   float th = 0.5f * theta[l * 8 + 6];
            float ct = __cosf(th), st = __sinf(th);
            #pragma unroll
            for (int jj = 0; jj < 2; ++jj) {
                float r0 = re[jj], i0 = im[jj], r1 = re[jj + 2], i1 = im[jj + 2];
                re[jj]     = fmaf(ct, r0, -st * r1);
                im[jj]     = fmaf(ct, i0, -st * i1);
                re[jj + 2] = fmaf(ct, r1,  st * r0);
                im[jj + 2] = fmaf(ct, i1,  st * i0);
            }
        }
        {   float th = 0.5f * theta[l * 8 + 7];
            float ct = __cosf(th), st = __sinf(th);
            #pragma unroll
            for (int jj = 0; jj < 4; jj += 2) {
                float r0 = re[jj], i0 = im[jj], r1 = re[jj + 1], i1 = im[jj + 1];
                re[jj]     = fmaf(ct, r0, -st * r1);
                im[jj]     = fmaf(ct, i0, -st * i1);
                re[jj + 1] = fmaf(ct, r1,  st * r0);
                im[jj + 1] = fmaf(ct, i1,  st * i0);
            }
        }
        #pragma unroll
        for (int q = 0; q < 5; ++q) {
            const int tm = 1 << (4 - q);
            const bool cb = (lane >> (5 - q)) & 1;
            #pragma unroll
            for (int jj = 0; jj < 4; ++jj) {
                float orr = shflx(re[jj], tm), oi = shflx(im[jj], tm);
                re[jj] = cb ? orr : re[jj];
                im[jj] = cb ? oi  : im[jj];
            }
        }
        {   const bool cb = lane & 1;
            float t;
            t = re[0]; re[0] = cb ? re[2] : re[0]; re[2] = cb ? t : re[2];
            t = im[0]; im[0] = cb ? im[2] : im[0]; im[2] = cb ? t : im[2];
            t = re[1]; re[1] = cb ? re[3] : re[1]; re[3] = cb ? t : re[3];
            t = im[1]; im[1] = cb ? im[3] : im[1]; im[3] = cb ? t : im[3];
        }
        {   float t;
            t = re[2]; re[2] = re[3]; re[3] = t;
            t = im[2]; im[2] = im[3]; im[3] = t;
        }
        {   re[1] = shflx(re[1], 32); im[1] = shflx(im[1], 32);
            re[3] = shflx(re[3], 32); im[3] = shflx(im[3], 32);
        }
        float al = 0.f;
        #pragma unroll
        for (int q = 0; q < 6; ++q) {
            float h = 0.5f * phi[l * 8 + q];
            al += ((lane >> (5 - q)) & 1) ? h : -h;
        }
        float h6 = 0.5f * phi[l * 8 + 6], h7 = 0.5f * phi[l * 8 + 7];
        float ajs[4] = { al - h6 - h7, al - h6 + h7, al + h6 - h7, al + h6 + h7 };
        #pragma unroll
        for (int jj = 0; jj < 4; ++jj) {
            float cc = __cosf(ajs[jj]), sn = __sinf(ajs[jj]);
            float r = re[jj], i = im[jj];
            re[jj] = r * cc - i * sn;
            im[jj] = fmaf(r, sn, i * cc);
        }
    }

    #pragma unroll
    for (int jj = 0; jj < 4; ++jj) {
        int kp = lane * 4 + jj;
        Bmat[(size_t)kp * 256 + j]         = f2bf(re[jj]);
        Bmat[(size_t)(kp + 256) * 256 + j] = f2bf(im[jj]);
    }
}

// ---------------------------------------------------------------------------
// K2: mega-fused, 64 samples / 1024 threads (16 waves) / block, grid = B/64.
// encode -> psi(bf16,LDS) -> GEMM1 (MFMA; wave w owns cols w*16..+15, re+im)
// -> probs bf16 (alias psi) -> chunked signed reduce -> z -> MLP1 -> h bf16
// (alias) -> GEMM2 MFMA -> out = x + b2 + D.
// MFMA maps (HW-verified): A/B row=lane&15, k=quad*8+j; C/D col=lane&15,
// row=quad*4+reg.
// ---------------------------------------------------------------------------
__global__ __launch_bounds__(1024) void vqc_mega_kernel(
    const float* __restrict__ x,
    const unsigned short* __restrict__ Bmat,  // (512,256) bf16
    const unsigned short* __restrict__ W2T,   // (256,128) bf16
    const float* __restrict__ W1,             // (8,128)
    const float* __restrict__ b1,             // (128)
    const float* __restrict__ b2,             // (256)
    float* __restrict__ out)
{
    __shared__ __align__(16) unsigned short region[NS * PSTR];  // 33792 B
    __shared__ __align__(16) float zp_lds[NS * ZPSTR];          // 17408 B
    __shared__ float z_lds[NS][8];                              // 2048 B

    unsigned short (*psi)[PSTR]  = (unsigned short(*)[PSTR])region;
    unsigned short (*hmat)[HSTR] = (unsigned short(*)[HSTR])region;

    const int t = threadIdx.x;
    const int lane = t & 63;
    const int w = t >> 6;       // wave 0..15
    const int c = lane & 15;
    const int quad = lane >> 4;
    const int s0 = blockIdx.x * NS;

    // ---- encode: 16 threads / sample, thread owns amps sub*16..sub*16+15 ----
    {
        const int g = t >> 4;     // local sample 0..63
        const int sub = t & 15;
        const float4* xr = reinterpret_cast<const float4*>(x + (size_t)(s0 + g) * 256) + sub * 4;
        float4 v0 = xr[0], v1 = xr[1], v2 = xr[2], v3 = xr[3];
        float mn = fminf(fminf(fminf(v0.x, v0.y), fminf(v0.z, v0.w)),
                         fminf(fminf(v1.x, v1.y), fminf(v1.z, v1.w)));
        mn = fminf(mn, fminf(fminf(fminf(v2.x, v2.y), fminf(v2.z, v2.w)),
                             fminf(fminf(v3.x, v3.y), fminf(v3.z, v3.w))));
        float mx = fmaxf(fmaxf(fmaxf(v0.x, v0.y), fmaxf(v0.z, v0.w)),
                         fmaxf(fmaxf(v1.x, v1.y), fmaxf(v1.z, v1.w)));
        mx = fmaxf(mx, fmaxf(fmaxf(fmaxf(v2.x, v2.y), fmaxf(v2.z, v2.w)),
                             fmaxf(fmaxf(v3.x, v3.y), fmaxf(v3.z, v3.w))));
        #pragma unroll
        for (int m = 1; m < 16; m <<= 1) {
            mn = fminf(mn, shflx(mn, m));
            mx = fmaxf(mx, shflx(mx, m));
        }
        const float scale = 0.78539816339744831f / (mx - mn + 1e-8f);  // half-angle

        const int base = lane & 48;  // sub==0 lane of the 16-lane group
        float xq[8];
        xq[0] = __shfl(v0.x, base); xq[1] = __shfl(v0.y, base);
        xq[2] = __shfl(v0.z, base); xq[3] = __shfl(v0.w, base);
        xq[4] = __shfl(v1.x, base); xq[5] = __shfl(v1.y, base);
        xq[6] = __shfl(v1.z, base); xq[7] = __shfl(v1.w, base);

        float cq[8], sq[8];
        #pragma unroll
        for (int q = 0; q < 8; ++q) {
            float a = (xq[q] - mn) * scale;
            cq[q] = __cosf(a);
            sq[q] = __sinf(a);
        }
        // amp idx = sub*16 + nl; qubit q <-> idx bit (7-q); sub = bits 7..4
        float pref = ((sub & 8) ? sq[0] : cq[0]) *
                     ((sub & 4) ? sq[1] : cq[1]) *
                     ((sub & 2) ? sq[2] : cq[2]) *
                     ((sub & 1) ? sq[3] : cq[3]);
        float p1[2], p2[4], p3[8];
        p1[0] = pref * cq[4]; p1[1] = pref * sq[4];
        #pragma unroll
        for (int i = 0; i < 2; ++i) { p2[2*i] = p1[i] * cq[5]; p2[2*i+1] = p1[i] * sq[5]; }
        #pragma unroll
        for (int i = 0; i < 4; ++i) { p3[2*i] = p2[i] * cq[6]; p3[2*i+1] = p2[i] * sq[6]; }
        #pragma unroll
        for (int i = 0; i < 4; ++i) {
            ushort4 pk;
            pk.x = f2bf(p3[2*i]     * cq[7]);
            pk.y = f2bf(p3[2*i]     * sq[7]);
            pk.z = f2bf(p3[2*i + 1] * cq[7]);
            pk.w = f2bf(p3[2*i + 1] * sq[7]);
            *reinterpret_cast<ushort4*>(&psi[g][sub * 16 + 4 * i]) = pk;
        }
    }
    __syncthreads();

    // ---- GEMM1: wave w -> cols n = w*16+c of Phi_re and Phi_im ----
    float4v accre[4], accim[4];
    #pragma unroll
    for (int mt = 0; mt < 4; ++mt) {
        accre[mt] = (float4v){0.f, 0.f, 0.f, 0.f};
        accim[mt] = (float4v){0.f, 0.f, 0.f, 0.f};
    }
    #pragma unroll
    for (int kk = 0; kk < 8; ++kk) {
        const int ko = kk * 32 + quad * 8;
        short8 a0 = *(const short8*)(&psi[c][ko]);
        short8 a1 = *(const short8*)(&psi[16 + c][ko]);
        short8 a2 = *(const short8*)(&psi[32 + c][ko]);
        short8 a3 = *(const short8*)(&psi[48 + c][ko]);
        short8 bre = *(const short8*)(Bmat + (size_t)(w * 16 + c) * 256 + ko);
        short8 bim = *(const short8*)(Bmat + (size_t)(256 + w * 16 + c) * 256 + ko);
        accre[0] = __builtin_amdgcn_mfma_f32_16x16x32_bf16(a0, bre, accre[0], 0, 0, 0);
        accre[1] = __builtin_amdgcn_mfma_f32_16x16x32_bf16(a1, bre, accre[1], 0, 0, 0);
        accre[2] = __builtin_amdgcn_mfma_f32_16x16x32_bf16(a2, bre, accre[2], 0, 0, 0);
        accre[3] = __builtin_amdgcn_mfma_f32_16x16x32_bf16(a3, bre, accre[3], 0, 0, 0);
        accim[0] = __builtin_amdgcn_mfma_f32_16x16x32_bf16(a0, bim, accim[0], 0, 0, 0);
        accim[1] = __builtin_amdgcn_mfma_f32_16x16x32_bf16(a1, bim, accim[1], 0, 0, 0);
        accim[2] = __builtin_amdgcn_mfma_f32_16x16x32_bf16(a2, bim, accim[2], 0, 0, 0);
        accim[3] = __builtin_amdgcn_mfma_f32_16x16x32_bf16(a3, bim, accim[3], 0, 0, 0);
    }
    __syncthreads();  // psi reads done before p overwrites region

    // ---- probs (bf16) into region ----
    #pragma unroll
    for (int mt = 0; mt < 4; ++mt)
        #pragma unroll
        for (int r = 0; r < 4; ++r) {
            const int m = mt * 16 + quad * 4 + r;
            const float pr = accre[mt][r], pi = accim[mt][r];
            psi[m][w * 16 + c] = f2bf(pr * pr + pi * pi);
        }
    __syncthreads();

    // ---- chunked signed reduce: thread (m, h) covers cols h*32..h*32+31 ----
    if (t < 512) {
        const int m = t >> 3, h = t & 7;
        const uint4* pu = (const uint4*)(&psi[m][h * 32]);  // 4x16B = 32 bf16
        float s[8], d6s = 0.f, d7s = 0.f;
        #pragma unroll
        for (int i = 0; i < 4; ++i) {
            uint4 u = pu[i];
            {   float e0 = bfbits(u.x << 16), e1 = bfbits(u.x & 0xffff0000u);
                float e2 = bfbits(u.y << 16), e3 = bfbits(u.y & 0xffff0000u);
                float a01 = e0 + e1, a23 = e2 + e3;
                s[2*i] = a01 + a23;
                d6s += a01 - a23;
                d7s += (e0 - e1) + (e2 - e3);
            }
            {   float e0 = bfbits(u.z << 16), e1 = bfbits(u.z & 0xffff0000u);
                float e2 = bfbits(u.w << 16), e3 = bfbits(u.w & 0xffff0000u);
                float a01 = e0 + e1, a23 = e2 + e3;
                s[2*i+1] = a01 + a23;
                d6s += a01 - a23;
                d7s += (e0 - e1) + (e2 - e3);
            }
        }
        float t01 = s[0] + s[1], t23 = s[2] + s[3], t45 = s[4] + s[5], t67 = s[6] + s[7];
        float u03 = t01 + t23, u47 = t45 + t67;
        float S  = u03 + u47;
        float S3 = u03 - u47;                       // n bit4
        float S4 = (t01 - t23) + (t45 - t67);       // n bit3
        float S5 = (s[0]-s[1]) + (s[2]-s[3]) + (s[4]-s[5]) + (s[6]-s[7]);  // n bit2
        float* zr = &zp_lds[m * ZPSTR + h * 8];
        zr[0] = (h & 4) ? -S : S;   // q0 <- n bit7 = h bit2
        zr[1] = (h & 2) ? -S : S;   // q1 <- n bit6
        zr[2] = (h & 1) ? -S : S;   // q2 <- n bit5
        zr[3] = S3; zr[4] = S4; zr[5] = S5; zr[6] = d6s; zr[7] = d7s;
    }
    __syncthreads();

    // ---- combine partials -> z ----
    if (t < 512) {
        const int m = t >> 3, q = t & 7;
        float zv = 0.f;
        #pragma unroll
        for (int h = 0; h < 8; ++h) zv += zp_lds[m * ZPSTR + h * 8 + q];
        z_lds[m][q] = zv;
    }
    __syncthreads();

    // ---- MLP1: h = relu(z@W1 + b1) -> bf16 (alias region) ----
    {
        const int j = t & 127, ig = t >> 7;
        float w1v[8];
        #pragma unroll
        for (int q = 0; q < 8; ++q) w1v[q] = W1[q * 128 + j];
        const float b1v = b1[j];
        #pragma unroll
        for (int ii = 0; ii < 8; ++ii) {
            const int i = ig * 8 + ii;
            float a = b1v;
            #pragma unroll
            for (int q = 0; q < 8; ++q) a = fmaf(z_lds[i][q], w1v[q], a);
            hmat[i][j] = f2bf(fmaxf(a, 0.f));
        }
    }
    __syncthreads();

    // ---- GEMM2: wave w -> cols n = w*16+c of h @ W2 ----
    float4v acc2[4];
    #pragma unroll
    for (int mt = 0; mt < 4; ++mt) acc2[mt] = (float4v){0.f, 0.f, 0.f, 0.f};
    #pragma unroll
    for (int kk = 0; kk < 4; ++kk) {
        const int ko = kk * 32 + quad * 8;
        short8 a0 = *(const short8*)(&hmat[c][ko]);
        short8 a1 = *(const short8*)(&hmat[16 + c][ko]);
        short8 a2 = *(const short8*)(&hmat[32 + c][ko]);
        short8 a3 = *(const short8*)(&hmat[48 + c][ko]);
        short8 bw = *(const short8*)(W2T + (size_t)(w * 16 + c) * 128 + ko);
        acc2[0] = __builtin_amdgcn_mfma_f32_16x16x32_bf16(a0, bw, acc2[0], 0, 0, 0);
        acc2[1] = __builtin_amdgcn_mfma_f32_16x16x32_bf16(a1, bw, acc2[1], 0, 0, 0);
        acc2[2] = __builtin_amdgcn_mfma_f32_16x16x32_bf16(a2, bw, acc2[2], 0, 0, 0);
        acc2[3] = __builtin_amdgcn_mfma_f32_16x16x32_bf16(a3, bw, acc2[3], 0, 0, 0);
    }

    // ---- epilogue: out = x + b2 + D ----
    {
        const int n = w * 16 + c;
        const float b2v = b2[n];
        #pragma unroll
        for (int mt = 0; mt < 4; ++mt)
            #pragma unroll
            for (int r = 0; r < 4; ++r) {
                const int m = mt * 16 + quad * 4 + r;
                const size_t idx = (size_t)(s0 + m) * 256 + n;
                out[idx] = x[idx] + b2v + acc2[mt][r];
            }
    }
}

extern "C" void kernel_launch(void* const* d_in, const int* in_sizes, int n_in,
                              void* d_out, int out_size, void* d_ws, size_t ws_size,
                              hipStream_t stream) {
    const float* x     = (const float*)d_in[0];
    const float* theta = (const float*)d_in[1];
    const float* phi   = (const float*)d_in[2];
    const float* W1    = (const float*)d_in[3];
    const float* b1    = (const float*)d_in[4];
    const float* W2    = (const float*)d_in[5];
    const float* b2    = (const float*)d_in[6];
    float* out = (float*)d_out;
    const int B = in_sizes[0] / 256;

    unsigned short* Bmat = (unsigned short*)d_ws;   // (512,256) bf16
    unsigned short* W2T  = Bmat + 512 * 256;        // (256,128) bf16

    vqc_build_u_kernel<<<dim3(96), dim3(256), 0, stream>>>(theta, phi, W2, Bmat, W2T);
    vqc_mega_kernel<<<dim3(B / NS), dim3(1024), 0, stream>>>(
        x, Bmat, W2T, W1, b1, b2, out);
}